// Round 1
// baseline (1448.857 us; speedup 1.0000x reference)
//
#include <hip/hip_runtime.h>

#define N_NODES 50000
#define N_EDGES 800000
#define D 128

// ---------------------------------------------------------------------------
// Kernel A: out[n][o] = b[o]   (bias init; scatter adds on top)
// ---------------------------------------------------------------------------
__global__ void init_bias_kernel(float* __restrict__ out, const float* __restrict__ b,
                                 int total4) {
    int idx = blockIdx.x * blockDim.x + threadIdx.x;
    if (idx >= total4) return;
    float4 b4 = reinterpret_cast<const float4*>(b)[idx & 31];  // 32 float4 = 128 floats
    reinterpret_cast<float4*>(out)[idx] = b4;
}

// ---------------------------------------------------------------------------
// Kernel B: H[n][o] = sum_d X[n][d] * W[o][d]      (H = X @ W^T)
// W staged in LDS transposed with (o+d)&127 swizzle:
//   Wt[d*128 + ((o+d)&127)] = W[o*128+d]
//   - read side: lanes vary o at fixed d -> banks (o+d)%32, 2 lanes/bank (free)
//   - store side: thread fixes o, varies d -> banks rotate (4-way worst, cheap)
// x rows staged in LDS; reads are wave-uniform (broadcast, conflict-free).
// Block = 256 threads; 8 rows/block; 50000/8 = 6250 blocks exactly (no tail).
// ---------------------------------------------------------------------------
__global__ __launch_bounds__(256) void gemm_xwT_kernel(const float* __restrict__ X,
                                                       const float* __restrict__ W,
                                                       float* __restrict__ H) {
    __shared__ float Wt[D * D];   // 64 KiB
    __shared__ float xs[8 * D];   // 4 KiB
    const int t = threadIdx.x;

    // Stage W transposed+swizzled: 4096 float4 loads / 256 threads = 16 each.
    for (int i = 0; i < 16; ++i) {
        int idx4 = t + i * 256;                 // float4 index into W
        float4 w4 = reinterpret_cast<const float4*>(W)[idx4];
        int o = idx4 >> 5;                      // (idx4*4)/128
        int d = (idx4 << 2) & 127;
        Wt[(d + 0) * D + ((o + d + 0) & 127)] = w4.x;
        Wt[(d + 1) * D + ((o + d + 1) & 127)] = w4.y;
        Wt[(d + 2) * D + ((o + d + 2) & 127)] = w4.z;
        Wt[(d + 3) * D + ((o + d + 3) & 127)] = w4.w;
    }

    const int o    = t & 127;
    const int half = t >> 7;          // 0 or 1
    const int r0   = half * 4;
    const int base = blockIdx.x * 8;  // grid sized so base+8 <= N_NODES always

    // Stage 8 rows of X (1024 floats = 256 float4; one per thread).
    {
        int r  = t >> 5;
        int d4 = t & 31;
        float4 x4 = reinterpret_cast<const float4*>(X + (size_t)(base + r) * D)[d4];
        reinterpret_cast<float4*>(xs)[t] = x4;
    }
    __syncthreads();

    float acc0 = 0.f, acc1 = 0.f, acc2 = 0.f, acc3 = 0.f;
    #pragma unroll 8
    for (int d = 0; d < D; ++d) {
        float w = Wt[d * D + ((o + d) & 127)];
        acc0 += xs[(r0 + 0) * D + d] * w;
        acc1 += xs[(r0 + 1) * D + d] * w;
        acc2 += xs[(r0 + 2) * D + d] * w;
        acc3 += xs[(r0 + 3) * D + d] * w;
    }

    H[(size_t)(base + r0 + 0) * D + o] = acc0;
    H[(size_t)(base + r0 + 1) * D + o] = acc1;
    H[(size_t)(base + r0 + 2) * D + o] = acc2;
    H[(size_t)(base + r0 + 3) * D + o] = acc3;
}

// ---------------------------------------------------------------------------
// Kernel C: for each edge e: out[row[e]][:] += vals[e] * H[col[e]][:]
// One thread per (edge, 4-col group): 32 threads/edge, float4 gather of H,
// 4 scalar f32 atomics into out.
// ---------------------------------------------------------------------------
__global__ void scatter_edges_kernel(const int* __restrict__ row,
                                     const int* __restrict__ col,
                                     const float* __restrict__ vals,
                                     const float* __restrict__ H,
                                     float* __restrict__ out, int total) {
    int idx = blockIdx.x * blockDim.x + threadIdx.x;
    if (idx >= total) return;            // total = N_EDGES * 32
    int e = idx >> 5;
    int q = idx & 31;
    int r = row[e];
    int c = col[e];
    float v = vals[e];
    float4 h4 = reinterpret_cast<const float4*>(H)[c * 32 + q];
    float* dst = out + (size_t)r * D + (q << 2);
    atomicAdd(dst + 0, v * h4.x);
    atomicAdd(dst + 1, v * h4.y);
    atomicAdd(dst + 2, v * h4.z);
    atomicAdd(dst + 3, v * h4.w);
}

// ---------------------------------------------------------------------------
extern "C" void kernel_launch(void* const* d_in, const int* in_sizes, int n_in,
                              void* d_out, int out_size, void* d_ws, size_t ws_size,
                              hipStream_t stream) {
    const int*   adj_row  = (const int*)d_in[0];
    const int*   adj_col  = (const int*)d_in[1];
    const float* adj_vals = (const float*)d_in[2];
    const float* features = (const float*)d_in[3];
    const float* W        = (const float*)d_in[4];
    const float* b        = (const float*)d_in[5];
    float*       out      = (float*)d_out;
    float*       H        = (float*)d_ws;   // N_NODES * D floats = 25.6 MB

    // A: out = b (broadcast)
    {
        int total4 = N_NODES * (D / 4);
        int blocks = (total4 + 255) / 256;
        init_bias_kernel<<<blocks, 256, 0, stream>>>(out, b, total4);
    }
    // B: H = X @ W^T
    {
        int blocks = N_NODES / 8;  // 6250, exact
        gemm_xwT_kernel<<<blocks, 256, 0, stream>>>(features, W, H);
    }
    // C: scatter-add edges into out
    {
        int total  = N_EDGES * 32;
        int blocks = (total + 255) / 256;
        scatter_edges_kernel<<<blocks, 256, 0, stream>>>(adj_row, adj_col, adj_vals,
                                                         H, out, total);
    }
}

// Round 2
// 361.978 us; speedup vs baseline: 4.0026x; 4.0026x over previous
//
#include <hip/hip_runtime.h>

#define N_NODES 50000
#define N_EDGES 800000
#define D 128

// ---------------------------------------------------------------------------
// Workspace layout (bytes, all 16B-aligned):
//   H       : N_NODES*D floats      = 25,600,000
//   counts  : N_NODES ints          =    200,000
//   offsets : (N_NODES+1) ints      =    200,016 (padded)
//   cursor  : N_NODES ints          =    200,000
//   scol    : N_EDGES ints          =  3,200,000
//   sval    : N_EDGES floats        =  3,200,000
//   total   ~ 32.6 MB
// ---------------------------------------------------------------------------
#define WS_H_OFF       0
#define WS_COUNTS_OFF  (25600000)
#define WS_OFFSETS_OFF (WS_COUNTS_OFF + 200000)
#define WS_CURSOR_OFF  (WS_OFFSETS_OFF + 200016)
#define WS_SCOL_OFF    (WS_CURSOR_OFF + 200000)
#define WS_SVAL_OFF    (WS_SCOL_OFF + 3200000)

// ---------------------------------------------------------------------------
// Zero the counts array.
// ---------------------------------------------------------------------------
__global__ void zero_counts_kernel(int* __restrict__ counts, int n) {
    int i = blockIdx.x * blockDim.x + threadIdx.x;
    if (i < n) counts[i] = 0;
}

// ---------------------------------------------------------------------------
// Histogram: counts[row[e]]++
// ---------------------------------------------------------------------------
__global__ void hist_kernel(const int* __restrict__ row, int* __restrict__ counts) {
    int e = blockIdx.x * blockDim.x + threadIdx.x;
    if (e < N_EDGES) atomicAdd(&counts[row[e]], 1);
}

// ---------------------------------------------------------------------------
// Single-block exclusive scan of counts -> offsets[0..N], and cursor copy.
// 1024 threads, each handles a contiguous chunk of 49 elements.
// ---------------------------------------------------------------------------
__global__ __launch_bounds__(1024) void scan_kernel(const int* __restrict__ counts,
                                                    int* __restrict__ offsets,
                                                    int* __restrict__ cursor) {
    __shared__ int part[1024];
    const int t = threadIdx.x;
    const int CH = (N_NODES + 1023) / 1024;  // 49
    int begI = t * CH;
    int endI = begI + CH;
    if (begI > N_NODES) begI = N_NODES;
    if (endI > N_NODES) endI = N_NODES;

    int s = 0;
    for (int i = begI; i < endI; ++i) s += counts[i];
    part[t] = s;
    __syncthreads();

    // Hillis-Steele inclusive scan over 1024 partials.
    for (int off = 1; off < 1024; off <<= 1) {
        int v = part[t];
        int add = (t >= off) ? part[t - off] : 0;
        __syncthreads();
        part[t] = v + add;
        __syncthreads();
    }

    int prefix = (t == 0) ? 0 : part[t - 1];  // exclusive prefix of this chunk
    for (int i = begI; i < endI; ++i) {
        offsets[i] = prefix;
        cursor[i]  = prefix;
        prefix += counts[i];
    }
    if (t == 1023) offsets[N_NODES] = prefix;  // == total edges
}

// ---------------------------------------------------------------------------
// Bucket scatter: place (col, val) of each edge into its row's segment.
// ---------------------------------------------------------------------------
__global__ void bucket_kernel(const int* __restrict__ row, const int* __restrict__ col,
                              const float* __restrict__ vals, int* __restrict__ cursor,
                              int* __restrict__ scol, float* __restrict__ sval) {
    int e = blockIdx.x * blockDim.x + threadIdx.x;
    if (e >= N_EDGES) return;
    int r = row[e];
    int pos = atomicAdd(&cursor[r], 1);
    scol[pos] = col[e];
    sval[pos] = vals[e];
}

// ---------------------------------------------------------------------------
// Kernel B: H[n][o] = sum_d X[n][d] * W[o][d]      (H = X @ W^T)
// (unchanged from round 0; ~100us, revisit if it becomes the top dispatch)
// ---------------------------------------------------------------------------
__global__ __launch_bounds__(256) void gemm_xwT_kernel(const float* __restrict__ X,
                                                       const float* __restrict__ W,
                                                       float* __restrict__ H) {
    __shared__ float Wt[D * D];   // 64 KiB
    __shared__ float xs[8 * D];   // 4 KiB
    const int t = threadIdx.x;

    for (int i = 0; i < 16; ++i) {
        int idx4 = t + i * 256;
        float4 w4 = reinterpret_cast<const float4*>(W)[idx4];
        int o = idx4 >> 5;
        int d = (idx4 << 2) & 127;
        Wt[(d + 0) * D + ((o + d + 0) & 127)] = w4.x;
        Wt[(d + 1) * D + ((o + d + 1) & 127)] = w4.y;
        Wt[(d + 2) * D + ((o + d + 2) & 127)] = w4.z;
        Wt[(d + 3) * D + ((o + d + 3) & 127)] = w4.w;
    }

    const int o    = t & 127;
    const int half = t >> 7;
    const int r0   = half * 4;
    const int base = blockIdx.x * 8;

    {
        int r  = t >> 5;
        int d4 = t & 31;
        float4 x4 = reinterpret_cast<const float4*>(X + (size_t)(base + r) * D)[d4];
        reinterpret_cast<float4*>(xs)[t] = x4;
    }
    __syncthreads();

    float acc0 = 0.f, acc1 = 0.f, acc2 = 0.f, acc3 = 0.f;
    #pragma unroll 8
    for (int d = 0; d < D; ++d) {
        float w = Wt[d * D + ((o + d) & 127)];
        acc0 += xs[(r0 + 0) * D + d] * w;
        acc1 += xs[(r0 + 1) * D + d] * w;
        acc2 += xs[(r0 + 2) * D + d] * w;
        acc3 += xs[(r0 + 3) * D + d] * w;
    }

    H[(size_t)(base + r0 + 0) * D + o] = acc0;
    H[(size_t)(base + r0 + 1) * D + o] = acc1;
    H[(size_t)(base + r0 + 2) * D + o] = acc2;
    H[(size_t)(base + r0 + 3) * D + o] = acc3;
}

// ---------------------------------------------------------------------------
// Aggregate: one wave per output row. Lane owns 2 columns (float2).
//   out[row][:] = b[:] + sum_{i in segment(row)} sval[i] * H[scol[i]][:]
// ---------------------------------------------------------------------------
__global__ __launch_bounds__(256) void aggregate_rows_kernel(
        const int* __restrict__ offsets, const int* __restrict__ scol,
        const float* __restrict__ sval, const float* __restrict__ H,
        const float* __restrict__ b, float* __restrict__ out) {
    int gtid = blockIdx.x * blockDim.x + threadIdx.x;
    int row  = gtid >> 6;
    int lane = threadIdx.x & 63;
    if (row >= N_NODES) return;

    int beg = offsets[row];
    int end = offsets[row + 1];

    float2 acc = reinterpret_cast<const float2*>(b)[lane];

    int i = beg;
    for (; i + 1 < end; i += 2) {
        int   c0 = scol[i];
        int   c1 = scol[i + 1];
        float v0 = sval[i];
        float v1 = sval[i + 1];
        float2 h0 = reinterpret_cast<const float2*>(H + (size_t)c0 * D)[lane];
        float2 h1 = reinterpret_cast<const float2*>(H + (size_t)c1 * D)[lane];
        acc.x += v0 * h0.x + v1 * h1.x;
        acc.y += v0 * h0.y + v1 * h1.y;
    }
    if (i < end) {
        int   c0 = scol[i];
        float v0 = sval[i];
        float2 h0 = reinterpret_cast<const float2*>(H + (size_t)c0 * D)[lane];
        acc.x += v0 * h0.x;
        acc.y += v0 * h0.y;
    }

    reinterpret_cast<float2*>(out + (size_t)row * D)[lane] = acc;
}

// ---------------------------------------------------------------------------
extern "C" void kernel_launch(void* const* d_in, const int* in_sizes, int n_in,
                              void* d_out, int out_size, void* d_ws, size_t ws_size,
                              hipStream_t stream) {
    const int*   adj_row  = (const int*)d_in[0];
    const int*   adj_col  = (const int*)d_in[1];
    const float* adj_vals = (const float*)d_in[2];
    const float* features = (const float*)d_in[3];
    const float* W        = (const float*)d_in[4];
    const float* b        = (const float*)d_in[5];
    float*       out      = (float*)d_out;

    char* ws = (char*)d_ws;
    float* H       = (float*)(ws + WS_H_OFF);
    int*   counts  = (int*)  (ws + WS_COUNTS_OFF);
    int*   offsets = (int*)  (ws + WS_OFFSETS_OFF);
    int*   cursor  = (int*)  (ws + WS_CURSOR_OFF);
    int*   scol    = (int*)  (ws + WS_SCOL_OFF);
    float* sval    = (float*)(ws + WS_SVAL_OFF);

    // 1. zero counts
    zero_counts_kernel<<<(N_NODES + 255) / 256, 256, 0, stream>>>(counts, N_NODES);
    // 2. histogram of rows
    hist_kernel<<<N_EDGES / 256, 256, 0, stream>>>(adj_row, counts);
    // 3. prefix scan -> offsets, cursor
    scan_kernel<<<1, 1024, 0, stream>>>(counts, offsets, cursor);
    // 4. bucket (col,val) by row
    bucket_kernel<<<N_EDGES / 256, 256, 0, stream>>>(adj_row, adj_col, adj_vals,
                                                     cursor, scol, sval);
    // 5. H = X @ W^T (independent of 1-4)
    gemm_xwT_kernel<<<N_NODES / 8, 256, 0, stream>>>(features, W, H);
    // 6. aggregate rows: out = b + segment_sum(sval * H[scol])
    {
        int waves  = N_NODES;                     // one wave per row
        int blocks = (waves * 64 + 255) / 256;    // 12500
        aggregate_rows_kernel<<<blocks, 256, 0, stream>>>(offsets, scol, sval,
                                                          H, b, out);
    }
}

// Round 3
// 203.310 us; speedup vs baseline: 7.1263x; 1.7804x over previous
//
#include <hip/hip_runtime.h>

#define N_NODES 50000
#define N_EDGES 800000
#define D 128

// ---------------------------------------------------------------------------
// Workspace layout (bytes):
//   H        : N_NODES*D floats   = 25,600,000
//   counts   : N_NODES ints       =    200,000
//   offsets  : (N_NODES+1) ints   =    200,016 (padded)
//   cursor   : N_NODES ints       =    200,000
//   scol     : N_EDGES ints       =  3,200,000
//   sval     : N_EDGES floats     =  3,200,000
//   partials : 256 ints           =      1,024
//   blockoffs: 256 ints           =      1,024
// ---------------------------------------------------------------------------
#define WS_H_OFF       0
#define WS_COUNTS_OFF  (25600000)
#define WS_OFFSETS_OFF (WS_COUNTS_OFF + 200000)
#define WS_CURSOR_OFF  (WS_OFFSETS_OFF + 200016)
#define WS_SCOL_OFF    (WS_CURSOR_OFF + 200000)
#define WS_SVAL_OFF    (WS_SCOL_OFF + 3200000)
#define WS_PART_OFF    (WS_SVAL_OFF + 3200000)
#define WS_BOFF_OFF    (WS_PART_OFF + 1024)

#define SCAN_BLOCKS 196   // ceil(50000/256)

// ---------------------------------------------------------------------------
__global__ void zero_counts_kernel(int* __restrict__ counts, int n) {
    int i = blockIdx.x * blockDim.x + threadIdx.x;
    if (i < n) counts[i] = 0;
}

// ---------------------------------------------------------------------------
__global__ void hist_kernel(const int* __restrict__ row, int* __restrict__ counts) {
    int e = blockIdx.x * blockDim.x + threadIdx.x;
    if (e < N_EDGES) atomicAdd(&counts[row[e]], 1);
}

// ---------------------------------------------------------------------------
// Scan stage 1: per-block (256-elem) sums -> partials[block]
// ---------------------------------------------------------------------------
__global__ __launch_bounds__(256) void scan_partials_kernel(const int* __restrict__ counts,
                                                            int* __restrict__ partials) {
    __shared__ int red[4];
    int t = threadIdx.x;
    int i = blockIdx.x * 256 + t;
    int v = (i < N_NODES) ? counts[i] : 0;
    #pragma unroll
    for (int off = 32; off > 0; off >>= 1) v += __shfl_down(v, off, 64);
    if ((t & 63) == 0) red[t >> 6] = v;
    __syncthreads();
    if (t == 0) partials[blockIdx.x] = red[0] + red[1] + red[2] + red[3];
}

// ---------------------------------------------------------------------------
// Scan stage 2: single tiny block scans SCAN_BLOCKS partials -> blockoffs
// (exclusive). Also writes offsets[N_NODES] = total.
// ---------------------------------------------------------------------------
__global__ __launch_bounds__(256) void scan_block_kernel(const int* __restrict__ partials,
                                                         int* __restrict__ blockoffs,
                                                         int* __restrict__ offsets) {
    __shared__ int sh[256];
    int t = threadIdx.x;
    int v = (t < SCAN_BLOCKS) ? partials[t] : 0;
    sh[t] = v;
    __syncthreads();
    #pragma unroll
    for (int off = 1; off < 256; off <<= 1) {
        int x = sh[t];
        int a = (t >= off) ? sh[t - off] : 0;
        __syncthreads();
        sh[t] = x + a;
        __syncthreads();
    }
    blockoffs[t] = (t == 0) ? 0 : sh[t - 1];
    if (t == 255) offsets[N_NODES] = sh[255];
}

// ---------------------------------------------------------------------------
// Scan stage 3: per-block local exclusive scan + blockoff -> offsets, cursor
// ---------------------------------------------------------------------------
__global__ __launch_bounds__(256) void scan_final_kernel(const int* __restrict__ counts,
                                                         const int* __restrict__ blockoffs,
                                                         int* __restrict__ offsets,
                                                         int* __restrict__ cursor) {
    __shared__ int sh[256];
    int t = threadIdx.x;
    int i = blockIdx.x * 256 + t;
    int v = (i < N_NODES) ? counts[i] : 0;
    sh[t] = v;
    __syncthreads();
    #pragma unroll
    for (int off = 1; off < 256; off <<= 1) {
        int x = sh[t];
        int a = (t >= off) ? sh[t - off] : 0;
        __syncthreads();
        sh[t] = x + a;
        __syncthreads();
    }
    int excl = blockoffs[blockIdx.x] + ((t == 0) ? 0 : sh[t - 1]);
    if (i < N_NODES) {
        offsets[i] = excl;
        cursor[i]  = excl;
    }
}

// ---------------------------------------------------------------------------
__global__ void bucket_kernel(const int* __restrict__ row, const int* __restrict__ col,
                              const float* __restrict__ vals, int* __restrict__ cursor,
                              int* __restrict__ scol, float* __restrict__ sval) {
    int e = blockIdx.x * blockDim.x + threadIdx.x;
    if (e >= N_EDGES) return;
    int r = row[e];
    int pos = atomicAdd(&cursor[r], 1);
    scol[pos] = col[e];
    sval[pos] = vals[e];
}

// ---------------------------------------------------------------------------
// GEMM v2: H = X @ W^T, register-tiled.
// Block: 256 threads, 32 rows. Thread (rg = t>>5, cg = t&31) computes a
// 4x4 micro-tile: rows rg*4+rr, cols cg*4+cc.
// W in LDS d-major with rotation: Wt[d][ (o + (d & 124)) & 127 ] = W[o][d]
//   - read (uniform d, lanes vary cg): 32 distinct 16B quads over 512B -> conflict-free
//   - rotation keeps 4-col groups 16B-aligned for ds_read_b128
// xs plain [32][128]; reads broadcast within wave (2-way, free).
// LDS 80KB -> 2 blocks/CU.
// ---------------------------------------------------------------------------
__global__ __launch_bounds__(256) void gemm_xwT_kernel(const float* __restrict__ X,
                                                       const float* __restrict__ W,
                                                       float* __restrict__ H) {
    __shared__ float Wt[D * D];    // 64 KiB
    __shared__ float xs[32 * D];   // 16 KiB
    const int t = threadIdx.x;
    const int base = blockIdx.x * 32;

    // Stage W: 4096 float4 / 256 threads = 16 each, transposed+rotated.
    #pragma unroll
    for (int i = 0; i < 16; ++i) {
        int idx4 = t + i * 256;
        float4 w4 = reinterpret_cast<const float4*>(W)[idx4];
        int o  = idx4 >> 5;
        int d0 = (idx4 & 31) << 2;
        int oc = (o + d0) & 127;
        Wt[(d0 + 0) * D + oc] = w4.x;
        Wt[(d0 + 1) * D + oc] = w4.y;
        Wt[(d0 + 2) * D + oc] = w4.z;
        Wt[(d0 + 3) * D + oc] = w4.w;
    }

    // Stage 32 rows of X: 1024 float4 / 256 threads = 4 each (guard tail).
    #pragma unroll
    for (int i = 0; i < 4; ++i) {
        int idx4 = t + i * 256;
        int r  = idx4 >> 5;
        int d4 = idx4 & 31;
        int row = base + r;
        float4 x4 = {0.f, 0.f, 0.f, 0.f};
        if (row < N_NODES)
            x4 = reinterpret_cast<const float4*>(X + (size_t)row * D)[d4];
        reinterpret_cast<float4*>(xs)[idx4] = x4;
    }
    __syncthreads();

    const int rg = t >> 5;   // 0..7
    const int cg = t & 31;   // 0..31

    float acc[4][4];
    #pragma unroll
    for (int rr = 0; rr < 4; ++rr)
        #pragma unroll
        for (int cc = 0; cc < 4; ++cc) acc[rr][cc] = 0.f;

    #pragma unroll 4
    for (int d0 = 0; d0 < D; d0 += 4) {
        int jb = (cg * 4 + d0) & 127;   // rotated col base, 16B-aligned
        float4 wc[4];
        #pragma unroll
        for (int k = 0; k < 4; ++k)
            wc[k] = *reinterpret_cast<const float4*>(&Wt[(d0 + k) * D + jb]);
        float4 xr[4];
        #pragma unroll
        for (int rr = 0; rr < 4; ++rr)
            xr[rr] = *reinterpret_cast<const float4*>(&xs[(rg * 4 + rr) * D + d0]);

        #pragma unroll
        for (int rr = 0; rr < 4; ++rr) {
            const float xv[4] = {xr[rr].x, xr[rr].y, xr[rr].z, xr[rr].w};
            #pragma unroll
            for (int k = 0; k < 4; ++k) {
                acc[rr][0] += xv[k] * wc[k].x;
                acc[rr][1] += xv[k] * wc[k].y;
                acc[rr][2] += xv[k] * wc[k].z;
                acc[rr][3] += xv[k] * wc[k].w;
            }
        }
    }

    #pragma unroll
    for (int rr = 0; rr < 4; ++rr) {
        int row = base + rg * 4 + rr;
        if (row < N_NODES) {
            float4 v = {acc[rr][0], acc[rr][1], acc[rr][2], acc[rr][3]};
            reinterpret_cast<float4*>(H + (size_t)row * D)[cg] = v;
        }
    }
}

// ---------------------------------------------------------------------------
// Aggregate: one wave per output row. Lane owns 2 columns (float2).
//   out[row][:] = b[:] + sum_{i in segment(row)} sval[i] * H[scol[i]][:]
// ---------------------------------------------------------------------------
__global__ __launch_bounds__(256) void aggregate_rows_kernel(
        const int* __restrict__ offsets, const int* __restrict__ scol,
        const float* __restrict__ sval, const float* __restrict__ H,
        const float* __restrict__ b, float* __restrict__ out) {
    int gtid = blockIdx.x * blockDim.x + threadIdx.x;
    int row  = gtid >> 6;
    int lane = threadIdx.x & 63;
    if (row >= N_NODES) return;

    int beg = offsets[row];
    int end = offsets[row + 1];

    float2 acc = reinterpret_cast<const float2*>(b)[lane];

    int i = beg;
    for (; i + 1 < end; i += 2) {
        int   c0 = scol[i];
        int   c1 = scol[i + 1];
        float v0 = sval[i];
        float v1 = sval[i + 1];
        float2 h0 = reinterpret_cast<const float2*>(H + (size_t)c0 * D)[lane];
        float2 h1 = reinterpret_cast<const float2*>(H + (size_t)c1 * D)[lane];
        acc.x += v0 * h0.x + v1 * h1.x;
        acc.y += v0 * h0.y + v1 * h1.y;
    }
    if (i < end) {
        int   c0 = scol[i];
        float v0 = sval[i];
        float2 h0 = reinterpret_cast<const float2*>(H + (size_t)c0 * D)[lane];
        acc.x += v0 * h0.x;
        acc.y += v0 * h0.y;
    }

    reinterpret_cast<float2*>(out + (size_t)row * D)[lane] = acc;
}

// ---------------------------------------------------------------------------
extern "C" void kernel_launch(void* const* d_in, const int* in_sizes, int n_in,
                              void* d_out, int out_size, void* d_ws, size_t ws_size,
                              hipStream_t stream) {
    const int*   adj_row  = (const int*)d_in[0];
    const int*   adj_col  = (const int*)d_in[1];
    const float* adj_vals = (const float*)d_in[2];
    const float* features = (const float*)d_in[3];
    const float* W        = (const float*)d_in[4];
    const float* b        = (const float*)d_in[5];
    float*       out      = (float*)d_out;

    char* ws = (char*)d_ws;
    float* H         = (float*)(ws + WS_H_OFF);
    int*   counts    = (int*)  (ws + WS_COUNTS_OFF);
    int*   offsets   = (int*)  (ws + WS_OFFSETS_OFF);
    int*   cursor    = (int*)  (ws + WS_CURSOR_OFF);
    int*   scol      = (int*)  (ws + WS_SCOL_OFF);
    float* sval      = (float*)(ws + WS_SVAL_OFF);
    int*   partials  = (int*)  (ws + WS_PART_OFF);
    int*   blockoffs = (int*)  (ws + WS_BOFF_OFF);

    // 1. zero counts
    zero_counts_kernel<<<(N_NODES + 255) / 256, 256, 0, stream>>>(counts, N_NODES);
    // 2. histogram of rows
    hist_kernel<<<N_EDGES / 256, 256, 0, stream>>>(adj_row, counts);
    // 3. hierarchical scan -> offsets, cursor
    scan_partials_kernel<<<SCAN_BLOCKS, 256, 0, stream>>>(counts, partials);
    scan_block_kernel<<<1, 256, 0, stream>>>(partials, blockoffs, offsets);
    scan_final_kernel<<<SCAN_BLOCKS, 256, 0, stream>>>(counts, blockoffs, offsets, cursor);
    // 4. bucket (col,val) by row
    bucket_kernel<<<N_EDGES / 256, 256, 0, stream>>>(adj_row, adj_col, adj_vals,
                                                     cursor, scol, sval);
    // 5. H = X @ W^T
    gemm_xwT_kernel<<<(N_NODES + 31) / 32, 256, 0, stream>>>(features, W, H);
    // 6. aggregate rows: out = b + segment_sum(sval * H[scol])
    {
        int blocks = (N_NODES * 64 + 255) / 256;   // one wave per row
        aggregate_rows_kernel<<<blocks, 256, 0, stream>>>(offsets, scol, sval,
                                                          H, b, out);
    }
}

// Round 4
// 153.700 us; speedup vs baseline: 9.4265x; 1.3228x over previous
//
#include <hip/hip_runtime.h>

#define N_NODES 50000
#define N_EDGES 800000
#define D 128

// ---------------------------------------------------------------------------
// Workspace layout (bytes, 16B-aligned):
//   H16      : N_NODES*D bf16      = 12,800,000
//   counts   : N_NODES ints        =    200,000
//   offsets  : (N_NODES+1) ints    =    200,016 (padded)
//   rank     : N_EDGES ints        =  3,200,000
//   spair    : N_EDGES int2        =  6,400,000
//   partials : 256 ints            =      1,024
//   blockoffs: 256 ints            =      1,024
//   total ~ 22.8 MB
// ---------------------------------------------------------------------------
#define WS_H_OFF       0
#define WS_COUNTS_OFF  (12800000)
#define WS_OFFSETS_OFF (WS_COUNTS_OFF + 200000)
#define WS_RANK_OFF    (WS_OFFSETS_OFF + 200016)
#define WS_SPAIR_OFF   (WS_RANK_OFF + 3200000)
#define WS_PART_OFF    (WS_SPAIR_OFF + 6400000)
#define WS_BOFF_OFF    (WS_PART_OFF + 1024)

#define SCAN_BLOCKS 196   // ceil(50000/256)

// f32 -> bf16 with round-to-nearest-even
__device__ __forceinline__ unsigned int f2bf(float f) {
    unsigned int u = __float_as_uint(f);
    unsigned int r = u + 0x7FFFu + ((u >> 16) & 1u);
    return r >> 16;
}
__device__ __forceinline__ float bf_lo(unsigned int u) {
    return __uint_as_float(u << 16);
}
__device__ __forceinline__ float bf_hi(unsigned int u) {
    return __uint_as_float(u & 0xFFFF0000u);
}

// ---------------------------------------------------------------------------
__global__ void zero_counts_kernel(int* __restrict__ counts, int n) {
    int i = blockIdx.x * blockDim.x + threadIdx.x;
    if (i < n) counts[i] = 0;
}

// ---------------------------------------------------------------------------
// Histogram + per-edge rank: rank[e] = old count of row[e].
// 2 edges/thread for ILP (N_EDGES is even).
// ---------------------------------------------------------------------------
__global__ void hist_rank_kernel(const int* __restrict__ row,
                                 int* __restrict__ counts,
                                 int* __restrict__ rank) {
    int i = blockIdx.x * blockDim.x + threadIdx.x;
    int e = i * 2;
    if (e >= N_EDGES) return;
    int2 rr = *reinterpret_cast<const int2*>(row + e);
    int k0 = atomicAdd(&counts[rr.x], 1);
    int k1 = atomicAdd(&counts[rr.y], 1);
    *reinterpret_cast<int2*>(rank + e) = make_int2(k0, k1);
}

// ---------------------------------------------------------------------------
// Scan stage 1: per-block (256-elem) sums -> partials[block]
// ---------------------------------------------------------------------------
__global__ __launch_bounds__(256) void scan_partials_kernel(const int* __restrict__ counts,
                                                            int* __restrict__ partials) {
    __shared__ int red[4];
    int t = threadIdx.x;
    int i = blockIdx.x * 256 + t;
    int v = (i < N_NODES) ? counts[i] : 0;
    #pragma unroll
    for (int off = 32; off > 0; off >>= 1) v += __shfl_down(v, off, 64);
    if ((t & 63) == 0) red[t >> 6] = v;
    __syncthreads();
    if (t == 0) partials[blockIdx.x] = red[0] + red[1] + red[2] + red[3];
}

// ---------------------------------------------------------------------------
// Scan stage 2: single block scans SCAN_BLOCKS partials -> blockoffs (excl).
// ---------------------------------------------------------------------------
__global__ __launch_bounds__(256) void scan_block_kernel(const int* __restrict__ partials,
                                                         int* __restrict__ blockoffs,
                                                         int* __restrict__ offsets) {
    __shared__ int sh[256];
    int t = threadIdx.x;
    int v = (t < SCAN_BLOCKS) ? partials[t] : 0;
    sh[t] = v;
    __syncthreads();
    #pragma unroll
    for (int off = 1; off < 256; off <<= 1) {
        int x = sh[t];
        int a = (t >= off) ? sh[t - off] : 0;
        __syncthreads();
        sh[t] = x + a;
        __syncthreads();
    }
    blockoffs[t] = (t == 0) ? 0 : sh[t - 1];
    if (t == 255) offsets[N_NODES] = sh[255];
}

// ---------------------------------------------------------------------------
// Scan stage 3: per-block local exclusive scan + blockoff -> offsets
// ---------------------------------------------------------------------------
__global__ __launch_bounds__(256) void scan_final_kernel(const int* __restrict__ counts,
                                                         const int* __restrict__ blockoffs,
                                                         int* __restrict__ offsets) {
    __shared__ int sh[256];
    int t = threadIdx.x;
    int i = blockIdx.x * 256 + t;
    int v = (i < N_NODES) ? counts[i] : 0;
    sh[t] = v;
    __syncthreads();
    #pragma unroll
    for (int off = 1; off < 256; off <<= 1) {
        int x = sh[t];
        int a = (t >= off) ? sh[t - off] : 0;
        __syncthreads();
        sh[t] = x + a;
        __syncthreads();
    }
    if (i < N_NODES)
        offsets[i] = blockoffs[blockIdx.x] + ((t == 0) ? 0 : sh[t - 1]);
}

// ---------------------------------------------------------------------------
// Bucket (atomic-free): spair[offsets[row[e]] + rank[e]] = (col[e], vals[e])
// ---------------------------------------------------------------------------
__global__ void bucket_kernel(const int* __restrict__ row, const int* __restrict__ col,
                              const float* __restrict__ vals,
                              const int* __restrict__ offsets,
                              const int* __restrict__ rank,
                              int2* __restrict__ spair) {
    int e = blockIdx.x * blockDim.x + threadIdx.x;
    if (e >= N_EDGES) return;
    int r = row[e];
    int pos = offsets[r] + rank[e];
    spair[pos] = make_int2(col[e], __float_as_int(vals[e]));
}

// ---------------------------------------------------------------------------
// GEMM: H16 = bf16(X @ W^T), register-tiled (unchanged math from round 2).
// ---------------------------------------------------------------------------
__global__ __launch_bounds__(256) void gemm_xwT_kernel(const float* __restrict__ X,
                                                       const float* __restrict__ W,
                                                       unsigned int* __restrict__ H16) {
    __shared__ float Wt[D * D];    // 64 KiB
    __shared__ float xs[32 * D];   // 16 KiB
    const int t = threadIdx.x;
    const int base = blockIdx.x * 32;

    #pragma unroll
    for (int i = 0; i < 16; ++i) {
        int idx4 = t + i * 256;
        float4 w4 = reinterpret_cast<const float4*>(W)[idx4];
        int o  = idx4 >> 5;
        int d0 = (idx4 & 31) << 2;
        int oc = (o + d0) & 127;
        Wt[(d0 + 0) * D + oc] = w4.x;
        Wt[(d0 + 1) * D + oc] = w4.y;
        Wt[(d0 + 2) * D + oc] = w4.z;
        Wt[(d0 + 3) * D + oc] = w4.w;
    }

    #pragma unroll
    for (int i = 0; i < 4; ++i) {
        int idx4 = t + i * 256;
        int r  = idx4 >> 5;
        int d4 = idx4 & 31;
        int row = base + r;
        float4 x4 = {0.f, 0.f, 0.f, 0.f};
        if (row < N_NODES)
            x4 = reinterpret_cast<const float4*>(X + (size_t)row * D)[d4];
        reinterpret_cast<float4*>(xs)[idx4] = x4;
    }
    __syncthreads();

    const int rg = t >> 5;   // 0..7
    const int cg = t & 31;   // 0..31

    float acc[4][4];
    #pragma unroll
    for (int rr = 0; rr < 4; ++rr)
        #pragma unroll
        for (int cc = 0; cc < 4; ++cc) acc[rr][cc] = 0.f;

    #pragma unroll 4
    for (int d0 = 0; d0 < D; d0 += 4) {
        int jb = (cg * 4 + d0) & 127;
        float4 wc[4];
        #pragma unroll
        for (int k = 0; k < 4; ++k)
            wc[k] = *reinterpret_cast<const float4*>(&Wt[(d0 + k) * D + jb]);
        float4 xr[4];
        #pragma unroll
        for (int rr = 0; rr < 4; ++rr)
            xr[rr] = *reinterpret_cast<const float4*>(&xs[(rg * 4 + rr) * D + d0]);

        #pragma unroll
        for (int rr = 0; rr < 4; ++rr) {
            const float xv[4] = {xr[rr].x, xr[rr].y, xr[rr].z, xr[rr].w};
            #pragma unroll
            for (int k = 0; k < 4; ++k) {
                acc[rr][0] += xv[k] * wc[k].x;
                acc[rr][1] += xv[k] * wc[k].y;
                acc[rr][2] += xv[k] * wc[k].z;
                acc[rr][3] += xv[k] * wc[k].w;
            }
        }
    }

    #pragma unroll
    for (int rr = 0; rr < 4; ++rr) {
        int row = base + rg * 4 + rr;
        if (row < N_NODES) {
            uint2 packed;
            packed.x = f2bf(acc[rr][0]) | (f2bf(acc[rr][1]) << 16);
            packed.y = f2bf(acc[rr][2]) | (f2bf(acc[rr][3]) << 16);
            // uint index row*64 + cg*2 -> cols 4cg..4cg+3
            reinterpret_cast<uint2*>(H16 + (size_t)row * 64)[cg] = packed;
        }
    }
}

// ---------------------------------------------------------------------------
// Aggregate: one wave per row; lane owns cols (2*lane, 2*lane+1).
//   out[row][:] = b[:] + sum_i sval[i] * bf16(H[scol[i]][:])
// ---------------------------------------------------------------------------
__global__ __launch_bounds__(256) void aggregate_rows_kernel(
        const int* __restrict__ offsets, const int2* __restrict__ spair,
        const unsigned int* __restrict__ H16,
        const float* __restrict__ b, float* __restrict__ out) {
    int gtid = blockIdx.x * blockDim.x + threadIdx.x;
    int row  = gtid >> 6;
    int lane = threadIdx.x & 63;
    if (row >= N_NODES) return;

    int beg = offsets[row];
    int end = offsets[row + 1];

    float2 acc = reinterpret_cast<const float2*>(b)[lane];

    int i = beg;
    for (; i + 1 < end; i += 2) {
        int2 s0 = spair[i];
        int2 s1 = spair[i + 1];
        float v0 = __int_as_float(s0.y);
        float v1 = __int_as_float(s1.y);
        unsigned int h0 = H16[(size_t)s0.x * 64 + lane];
        unsigned int h1 = H16[(size_t)s1.x * 64 + lane];
        acc.x += v0 * bf_lo(h0) + v1 * bf_lo(h1);
        acc.y += v0 * bf_hi(h0) + v1 * bf_hi(h1);
    }
    if (i < end) {
        int2 s0 = spair[i];
        float v0 = __int_as_float(s0.y);
        unsigned int h0 = H16[(size_t)s0.x * 64 + lane];
        acc.x += v0 * bf_lo(h0);
        acc.y += v0 * bf_hi(h0);
    }

    reinterpret_cast<float2*>(out + (size_t)row * D)[lane] = acc;
}

// ---------------------------------------------------------------------------
extern "C" void kernel_launch(void* const* d_in, const int* in_sizes, int n_in,
                              void* d_out, int out_size, void* d_ws, size_t ws_size,
                              hipStream_t stream) {
    const int*   adj_row  = (const int*)d_in[0];
    const int*   adj_col  = (const int*)d_in[1];
    const float* adj_vals = (const float*)d_in[2];
    const float* features = (const float*)d_in[3];
    const float* W        = (const float*)d_in[4];
    const float* b        = (const float*)d_in[5];
    float*       out      = (float*)d_out;

    char* ws = (char*)d_ws;
    unsigned int* H16       = (unsigned int*)(ws + WS_H_OFF);
    int*          counts    = (int*)  (ws + WS_COUNTS_OFF);
    int*          offsets   = (int*)  (ws + WS_OFFSETS_OFF);
    int*          rank      = (int*)  (ws + WS_RANK_OFF);
    int2*         spair     = (int2*) (ws + WS_SPAIR_OFF);
    int*          partials  = (int*)  (ws + WS_PART_OFF);
    int*          blockoffs = (int*)  (ws + WS_BOFF_OFF);

    // 1. zero counts
    zero_counts_kernel<<<(N_NODES + 255) / 256, 256, 0, stream>>>(counts, N_NODES);
    // 2. histogram + per-edge rank (the only atomic pass)
    {
        int threads = N_EDGES / 2;
        hist_rank_kernel<<<(threads + 255) / 256, 256, 0, stream>>>(adj_row, counts, rank);
    }
    // 3. hierarchical scan -> offsets
    scan_partials_kernel<<<SCAN_BLOCKS, 256, 0, stream>>>(counts, partials);
    scan_block_kernel<<<1, 256, 0, stream>>>(partials, blockoffs, offsets);
    scan_final_kernel<<<SCAN_BLOCKS, 256, 0, stream>>>(counts, blockoffs, offsets);
    // 4. bucket (col,val) by row — atomic-free
    bucket_kernel<<<N_EDGES / 256, 256, 0, stream>>>(adj_row, adj_col, adj_vals,
                                                     offsets, rank, spair);
    // 5. H16 = bf16(X @ W^T)
    gemm_xwT_kernel<<<(N_NODES + 31) / 32, 256, 0, stream>>>(features, W, H16);
    // 6. aggregate rows: out = b + segment_sum(val * H[col])
    {
        int blocks = (N_NODES * 64 + 255) / 256;   // one wave per row
        aggregate_rows_kernel<<<blocks, 256, 0, stream>>>(offsets, spair, H16, b, out);
    }
}